// Round 8
// baseline (4187.974 us; speedup 1.0000x reference)
//
#include <hip/hip_runtime.h>
#include <stdint.h>

// CipherRNN: B=64, S=1024, V=128, E=512, H=512, L=2, O=256
#define B_ 64
#define S_ 1024
#define V_ 128
#define E_ 512
#define H_ 512
#define O_ 256
#define PSLOT (B_ * H_ * 2)     // 65536 u32 per ring slot of {data,tag} pairs

typedef __attribute__((ext_vector_type(8))) short bf16x8;
typedef __attribute__((ext_vector_type(4))) float f32x4;
typedef __attribute__((ext_vector_type(4))) unsigned int u32x4;
typedef __attribute__((ext_vector_type(2))) unsigned int u32x2;
typedef unsigned short u16;
typedef unsigned int u32;

__device__ __forceinline__ u16 f2bf(float f) {
  unsigned u = __builtin_bit_cast(unsigned, f);
  u = u + 0x7FFFu + ((u >> 16) & 1u);   // RNE
  return (u16)(u >> 16);
}
__device__ __forceinline__ float bf2f(u16 h) {
  unsigned u = ((unsigned)h) << 16;
  return __builtin_bit_cast(float, u);
}
// fast tanh via exp2 (~1e-7 rel err; numerically proven rounds 4/7)
__device__ __forceinline__ float fast_tanh(float x) {
  float a = __builtin_amdgcn_exp2f(x * 2.8853900817779268f);
  return 1.0f - 2.0f * __builtin_amdgcn_rcpf(a + 1.0f);
}
__device__ __forceinline__ u32 pk_hi(u32 a, u32 b) { return (a & 0xffffu) | (b << 16); }
__device__ __forceinline__ u32 pk_lo(u32 a, u32 b) { return (a >> 16) | (b & 0xffff0000u); }

// ---- L3-coherent (bypass L1+L2, zero cache-maintenance) ops — proven r3/r4/r7
__device__ __forceinline__ u32x4 ld_sc1_x4(const u32* p) {
  u32x4 v;
  asm volatile("global_load_dwordx4 %0, %1, off sc0 sc1" : "=v"(v) : "v"(p));
  return v;
}
__device__ __forceinline__ u32x2 ld_sc1_x2(const u32* p) {
  u32x2 v;
  asm volatile("global_load_dwordx2 %0, %1, off sc0 sc1" : "=v"(v) : "v"(p));
  return v;
}
__device__ __forceinline__ void st_sc1_x2(u32* p, u32 d, u32 tag) {
  u32x2 v = {d, tag};   // 8B aligned single store: pair is single-copy atomic (r4-proven)
  asm volatile("global_store_dwordx2 %0, %1, off sc0 sc1" :: "v"(p), "v"(v) : "memory");
}
__device__ __forceinline__ void st_sc1_u32(u32* p, u32 v) {
  asm volatile("global_store_dword %0, %1, off sc0 sc1" :: "v"(p), "v"(v) : "memory");
}
__device__ __forceinline__ void st_short_nt(u16* p, u32 v) {
  asm volatile("global_store_short %0, %1, off nt" :: "v"(p), "v"(v) : "memory");
}
__device__ __forceinline__ void vm0_fence() {
  asm volatile("s_waitcnt vmcnt(0)" ::: "memory");
  __builtin_amdgcn_sched_barrier(0);
}
// rare backpressure gate (off critical path)
__device__ __forceinline__ void poll4(const u32* p, u32 tgt) {
  for (;;) {
    u32x4 v;
    asm volatile("global_load_dwordx4 %0, %1, off sc0 sc1\n\ts_waitcnt vmcnt(0)"
                 : "=v"(v) : "v"(p) : "memory");
    if (v.x >= tgt && v.y >= tgt && v.z >= tgt && v.w >= tgt) return;
    __builtin_amdgcn_s_sleep(1);
  }
}

// ---------------------------------------------------------------------------
// EW0[v][n] = sum_e emb[v][e]*Wxh0[n][e] + bh0[n]   (f32 exact, V=128)
// ---------------------------------------------------------------------------
__global__ void k_embed(const float* __restrict__ emb, const float* __restrict__ Wxh0,
                        const float* __restrict__ bh0, float* __restrict__ EW0) {
  __shared__ float es[E_];
  const int v = blockIdx.x;
  for (int e = threadIdx.x; e < E_; e += blockDim.x) es[e] = emb[v * E_ + e];
  __syncthreads();
  for (int h = threadIdx.x; h < H_; h += blockDim.x) {
    const float* wr = Wxh0 + (size_t)h * E_;
    float acc = bh0[h];
    #pragma unroll 4
    for (int e = 0; e < E_; e += 4)
      acc += es[e] * wr[e] + es[e+1] * wr[e+1] + es[e+2] * wr[e+2] + es[e+3] * wr[e+3];
    EW0[(size_t)v * H_ + h] = acc;
  }
}

// ---------------------------------------------------------------------------
// Persistent 3-stage pipeline, FLAG-FREE: rings hold {data, tag=t+1} 8B pairs;
// consumers poll sibling data directly (tag match == arrival). No store-acks,
// no flag round trip. Lazy sc1 progress words give ring backpressure.
// 48 blocks = 3 roles x 4 groups (16 batch rows) x 4 col-blocks (128 cols).
// ---------------------------------------------------------------------------
__global__ __launch_bounds__(512, 2) void k_pipe(
    const float* __restrict__ Whh, const float* __restrict__ Wxh,
    const int* __restrict__ ids, const float* __restrict__ EW0,
    const float* __restrict__ bh,
    u32* __restrict__ h0r,        // [16][64*512] pairs {packed hb|lb, tag}
    u32* __restrict__ x1r,        // [16][64*512] pairs {f32 bits, tag}
    u32* __restrict__ h1r,        // [4][64*512] pairs
    u16* __restrict__ h1full,     // [B*S][512] bf16 (plain/nt cached)
    u32* __restrict__ fa)         // progress arena (zeroed each call)
{
  __shared__ u32 lds_hi_w[2 * 4096];   // 2 bufs x 16 rows x 512 u16 cols (hi)
  __shared__ u32 lds_lo_w[2 * 4096];   // (lo)

  const int tid  = threadIdx.x;
  const int wave = tid >> 6, lane = tid & 63;
  const int l15 = lane & 15, lhi = lane >> 4;
  const int bid = blockIdx.x;
  const int role = bid >> 4, sub = bid & 15;
  const int g = sub >> 2, cb = sub & 3;
  const int n = cb * 128 + wave * 16 + l15;   // this lane's output column

  u32* x1prog = fa;        // [4 groups][4 cb] role1 progress
  u32* r2prog = fa + 16;   // [4 groups][4 cb] role2 progress

  // ---- resident weights (hi/lo bf16 B-fragments), plain cached loads ----
  const float* Wsel = (role == 0) ? Whh
                    : (role == 1) ? (Wxh + (size_t)H_ * H_)
                                  : (Whh + (size_t)H_ * H_);
  bf16x8 whi[16], wlo[16];
  {
    const float* wr = Wsel + (size_t)n * H_ + lhi * 8;
    #pragma unroll
    for (int ks = 0; ks < 16; ++ks) {
      const float* src = wr + ks * 32;
      bf16x8 h, l;
      #pragma unroll
      for (int j = 0; j < 8; ++j) {
        const float v = src[j];
        const u16 hb = f2bf(v);
        h[j] = (short)hb;
        l[j] = (short)f2bf(v - bf2f(hb));
      }
      whi[ks] = h; wlo[ks] = l;
    }
  }

  // A-frag swizzled LDS byte offsets: row=l15, granule = ks*4+lhi (8 cols/granule)
  int aoff[16];
  {
    const int sw = l15 & 7;
    #pragma unroll
    for (int ks = 0; ks < 16; ++ks)
      aoff[ks] = l15 * 1024 + (((ks * 4 + lhi) ^ sw) << 4);
  }

  // staging geometry: 16 rows x 32 4-col chunks per slice
  const int sr = tid >> 5, sm = tid & 31;
  const int rowbase = (g * 16 + sr) * 512;     // pair-index row base in a slot

  // write 4 deinterleaved cols (granule half) into LDS buf with XOR swizzle
  auto wr_lds = [&](int buf, int cs, u32 d0, u32 d1, u32 d2, u32 d3) {
    const int byte = buf * 16384 + sr * 1024 + (sm & 1) * 8 +
                     ((((cs << 4) + (sm >> 1)) ^ (sr & 7)) << 4);
    u32x2 hi = { pk_hi(d0, d1), pk_hi(d2, d3) };
    u32x2 lo = { pk_lo(d0, d1), pk_lo(d2, d3) };
    *(u32x2*)((char*)lds_hi_w + byte) = hi;
    *(u32x2*)((char*)lds_lo_w + byte) = lo;
  };

  // poll+stage the 3 sibling 16x128 slices (own slice arrives via self_write)
  auto pollstage3 = [&](const u32* slot, u32 want, int buf) {
    const int c0 = (cb + 1) & 3, c1 = (cb + 2) & 3, c2 = (cb + 3) & 3;
    const u32* p0 = slot + ((rowbase + c0 * 128 + sm * 4) << 1);
    const u32* p1 = slot + ((rowbase + c1 * 128 + sm * 4) << 1);
    const u32* p2 = slot + ((rowbase + c2 * 128 + sm * 4) << 1);
    u32x4 a0, a1, b0, b1, d0, d1;
    for (;;) {
      a0 = ld_sc1_x4(p0); a1 = ld_sc1_x4(p0 + 4);
      b0 = ld_sc1_x4(p1); b1 = ld_sc1_x4(p1 + 4);
      d0 = ld_sc1_x4(p2); d1 = ld_sc1_x4(p2 + 4);
      vm0_fence();
      u32 bad = (a0.y ^ want) | (a0.w ^ want) | (a1.y ^ want) | (a1.w ^ want)
              | (b0.y ^ want) | (b0.w ^ want) | (b1.y ^ want) | (b1.w ^ want)
              | (d0.y ^ want) | (d0.w ^ want) | (d1.y ^ want) | (d1.w ^ want);
      if (!bad) break;
    }
    wr_lds(buf, c0, a0.x, a0.z, a1.x, a1.z);
    wr_lds(buf, c1, b0.x, b0.z, b1.x, b1.z);
    wr_lds(buf, c2, d0.x, d0.z, d1.x, d1.z);
  };

  // poll+stage all 4 slices (role 1: no local copy of any slice)
  auto pollstage4 = [&](const u32* slot, u32 want, int buf) {
    const u32* p0 = slot + ((rowbase + sm * 4) << 1);
    u32x4 q[8];
    for (;;) {
      #pragma unroll
      for (int c = 0; c < 4; ++c) {
        q[2*c]   = ld_sc1_x4(p0 + (c * 128 << 1));
        q[2*c+1] = ld_sc1_x4(p0 + (c * 128 << 1) + 4);
      }
      vm0_fence();
      u32 bad = 0;
      #pragma unroll
      for (int i = 0; i < 8; ++i) bad |= (q[i].y ^ want) | (q[i].w ^ want);
      if (!bad) break;
    }
    #pragma unroll
    for (int c = 0; c < 4; ++c)
      wr_lds(buf, c, q[2*c].x, q[2*c].z, q[2*c+1].x, q[2*c+1].z);
  };

  // emulated-fp32 matmul from LDS tile (3 independent MFMA chains)
  auto mm3 = [&](int buf, f32x4& out) {
    const char* bh_ = (const char*)lds_hi_w + buf * 16384;
    const char* bl_ = (const char*)lds_lo_w + buf * 16384;
    f32x4 c0 = {0.f,0.f,0.f,0.f}, c1 = c0, c2 = c0;
    #pragma unroll
    for (int ks = 0; ks < 16; ++ks) {
      bf16x8 ah = *(const bf16x8*)(bh_ + aoff[ks]);
      bf16x8 al = *(const bf16x8*)(bl_ + aoff[ks]);
      c0 = __builtin_amdgcn_mfma_f32_16x16x32_bf16(ah, whi[ks], c0, 0, 0, 0);
      c1 = __builtin_amdgcn_mfma_f32_16x16x32_bf16(al, whi[ks], c1, 0, 0, 0);
      c2 = __builtin_amdgcn_mfma_f32_16x16x32_bf16(ah, wlo[ks], c2, 0, 0, 0);
    }
    out = c0 + c1 + c2;
  };

  // epilogue self-write: own 4 outputs (col n, rows lhi*4+j) into LDS buf
  auto self_write = [&](int buf, const u16* hbv, const u16* lbv) {
    char* bh_ = (char*)lds_hi_w + buf * 16384;
    char* bl_ = (char*)lds_lo_w + buf * 16384;
    const int gcol = n >> 3, coff = (n & 7) * 2;
    #pragma unroll
    for (int j = 0; j < 4; ++j) {
      const int r = lhi * 4 + j;
      const int byte = r * 1024 + ((gcol ^ (r & 7)) << 4) + coff;
      *(u16*)(bh_ + byte) = hbv[j];
      *(u16*)(bl_ + byte) = lbv[j];
    }
  };

  if (role == 0) {                     // ======== layer-0 recurrence ========
    for (int t = 0; t < S_; ++t) {
      float ew[4];                      // plain cached, L2-hot
      #pragma unroll
      for (int j = 0; j < 4; ++j) {
        const int b = g * 16 + lhi * 4 + j;
        ew[j] = EW0[(size_t)ids[b * S_ + t] * H_ + n];
      }
      const int cur = t & 1;
      f32x4 acc = {0.f,0.f,0.f,0.f};
      if (t > 0) mm3(cur, acc);        // buf cur holds h[t-1] (staged last iter)
      // epilogue: compute h[t], store tagged pairs (fire-and-forget), self LDS
      u32* wsl = h0r + (size_t)(t & 15) * PSLOT;
      u16 hbv[4], lbv[4];
      #pragma unroll
      for (int j = 0; j < 4; ++j) {
        const int b = g * 16 + lhi * 4 + j;
        const float h = fast_tanh(acc[j] + ew[j]);
        hbv[j] = f2bf(h);
        lbv[j] = f2bf(h - bf2f(hbv[j]));
        st_sc1_x2(wsl + (((size_t)b * 512 + n) << 1),
                  (u32)hbv[j] | ((u32)lbv[j] << 16), (u32)(t + 1));
      }
      self_write(cur ^ 1, hbv, lbv);
      // lazy backpressure: h0r slot reuse needs role1 past t-16 (slack 8)
      if ((t & 7) == 0 && t >= 16 && tid == 0) poll4(&x1prog[g * 4], (u32)(t - 8));
      if (t + 1 < S_) pollstage3(wsl, (u32)(t + 1), cur ^ 1);
      __syncthreads();
    }
  } else if (role == 1) {              // ======== x1 = h0 @ Wxh1^T + bh1 ========
    const float bias = bh[H_ + n];
    for (int t = 0; t < S_; ++t) {
      if ((t & 7) == 0 && t >= 16 && tid == 0) poll4(&r2prog[g * 4], (u32)(t - 8));
      const int cur = t & 1;
      pollstage4(h0r + (size_t)(t & 15) * PSLOT, (u32)(t + 1), cur);
      __syncthreads();
      f32x4 acc;
      mm3(cur, acc);
      u32* xsl = x1r + (size_t)(t & 15) * PSLOT;
      #pragma unroll
      for (int j = 0; j < 4; ++j) {
        const int b = g * 16 + lhi * 4 + j;
        const float v = acc[j] + bias;
        st_sc1_x2(xsl + (((size_t)b * 512 + n) << 1),
                  __builtin_bit_cast(u32, v), (u32)(t + 1));
      }
      if ((t & 7) == 7 && tid == 0) st_sc1_u32(&x1prog[g * 4 + cb], (u32)(t + 1));
    }
  } else {                             // ======== layer-1 recurrence ========
    // x1 own-pair addresses (4 rows per lane)
    u32 xvb[4];
    {                                   // pre-loop: poll x1[0] (want tag 1)
      const u32* xsl = x1r;
      u32x2 xq[4];
      for (;;) {
        #pragma unroll
        for (int j = 0; j < 4; ++j) {
          const int b = g * 16 + lhi * 4 + j;
          xq[j] = ld_sc1_x2(xsl + (((size_t)b * 512 + n) << 1));
        }
        vm0_fence();
        u32 bad = 0;
        #pragma unroll
        for (int j = 0; j < 4; ++j) bad |= xq[j].y ^ 1u;
        if (!bad) break;
      }
      #pragma unroll
      for (int j = 0; j < 4; ++j) xvb[j] = xq[j].x;
    }
    for (int t = 0; t < S_; ++t) {
      const int cur = t & 1;
      f32x4 acc = {0.f,0.f,0.f,0.f};
      if (t > 0) mm3(cur, acc);        // buf cur holds h1[t-1]
      u32* wsl = h1r + (size_t)(t & 3) * PSLOT;
      u16 hbv[4], lbv[4];
      #pragma unroll
      for (int j = 0; j < 4; ++j) {
        const int b = g * 16 + lhi * 4 + j;
        const float h = fast_tanh(acc[j] + __builtin_bit_cast(float, xvb[j]));
        hbv[j] = f2bf(h);
        lbv[j] = f2bf(h - bf2f(hbv[j]));
        st_sc1_x2(wsl + (((size_t)b * 512 + n) << 1),
                  (u32)hbv[j] | ((u32)lbv[j] << 16), (u32)(t + 1));
        st_short_nt(h1full + ((size_t)b * S_ + t) * H_ + n, (u32)hbv[j]);
      }
      self_write(cur ^ 1, hbv, lbv);
      if ((t & 7) == 7 && tid == 0) st_sc1_u32(&r2prog[g * 4 + cb], (u32)(t + 1));
      if (t + 1 < S_) {
        // combined poll: sibling h1[t] slices (want t+1) + own x1[t+1] (want t+2)
        const u32 want = (u32)(t + 1), xwant = (u32)(t + 2);
        const int c0 = (cb + 1) & 3, c1 = (cb + 2) & 3, c2 = (cb + 3) & 3;
        const u32* p0 = wsl + ((rowbase + c0 * 128 + sm * 4) << 1);
        const u32* p1 = wsl + ((rowbase + c1 * 128 + sm * 4) << 1);
        const u32* p2 = wsl + ((rowbase + c2 * 128 + sm * 4) << 1);
        const u32* xsl = x1r + (size_t)((t + 1) & 15) * PSLOT;
        u32x4 a0, a1, b0, b1, d0, d1;
        u32x2 xq[4];
        for (;;) {
          a0 = ld_sc1_x4(p0); a1 = ld_sc1_x4(p0 + 4);
          b0 = ld_sc1_x4(p1); b1 = ld_sc1_x4(p1 + 4);
          d0 = ld_sc1_x4(p2); d1 = ld_sc1_x4(p2 + 4);
          #pragma unroll
          for (int j = 0; j < 4; ++j) {
            const int b = g * 16 + lhi * 4 + j;
            xq[j] = ld_sc1_x2(xsl + (((size_t)b * 512 + n) << 1));
          }
          vm0_fence();
          u32 bad = (a0.y ^ want) | (a0.w ^ want) | (a1.y ^ want) | (a1.w ^ want)
                  | (b0.y ^ want) | (b0.w ^ want) | (b1.y ^ want) | (b1.w ^ want)
                  | (d0.y ^ want) | (d0.w ^ want) | (d1.y ^ want) | (d1.w ^ want);
          #pragma unroll
          for (int j = 0; j < 4; ++j) bad |= xq[j].y ^ xwant;
          if (!bad) break;
        }
        wr_lds(cur ^ 1, c0, a0.x, a0.z, a1.x, a1.z);
        wr_lds(cur ^ 1, c1, b0.x, b0.z, b1.x, b1.z);
        wr_lds(cur ^ 1, c2, d0.x, d0.z, d1.x, d1.z);
        #pragma unroll
        for (int j = 0; j < 4; ++j) xvb[j] = xq[j].x;
      }
      __syncthreads();
    }
  }
}

// ---------------------------------------------------------------------------
// out = h1 @ Why^T + by. 64-row M-blocks (Why re-read /4 vs 16-row tiles).
// ---------------------------------------------------------------------------
__global__ void k_gemm_out(const u16* __restrict__ A, const float* __restrict__ Bw,
                           const float* __restrict__ bias, float* __restrict__ outp) {
  const int tid  = threadIdx.x;
  const int wave = tid >> 6, lane = tid & 63;
  const int l15 = lane & 15, lhi = lane >> 4;
  const int M0  = blockIdx.x * 64;
  const int ncb = wave * 64;

  #pragma unroll
  for (int nt = 0; nt < 4; ++nt) {
    const int nn = ncb + nt * 16 + l15;
    const float* wr = Bw + (size_t)nn * H_ + lhi * 8;
    bf16x8 w[16];
    #pragma unroll
    for (int ks = 0; ks < 16; ++ks) {
      const float* src = wr + ks * 32;
      bf16x8 ww;
      #pragma unroll
      for (int j = 0; j < 8; ++j) ww[j] = (short)f2bf(src[j]);
      w[ks] = ww;
    }
    const float bs = bias[nn];
    for (int mi = 0; mi < 4; ++mi) {
      const int m0 = M0 + mi * 16;
      const u16* arow = A + ((size_t)(m0 + l15)) * H_ + lhi * 8;
      f32x4 acc = {0.f, 0.f, 0.f, 0.f};
      #pragma unroll
      for (int ks = 0; ks < 16; ++ks) {
        bf16x8 a = *(const bf16x8*)(arow + ks * 32);
        acc = __builtin_amdgcn_mfma_f32_16x16x32_bf16(a, w[ks], acc, 0, 0, 0);
      }
      #pragma unroll
      for (int j = 0; j < 4; ++j)
        outp[(size_t)(m0 + lhi * 4 + j) * O_ + nn] = acc[j] + bs;
    }
  }
}

// ---------------------------------------------------------------------------
extern "C" void kernel_launch(void* const* d_in, const int* in_sizes, int n_in,
                              void* d_out, int out_size, void* d_ws, size_t ws_size,
                              hipStream_t stream) {
  const int*   ids = (const int*)d_in[0];
  const float* emb = (const float*)d_in[1];
  const float* Wxh = (const float*)d_in[2];
  const float* Whh = (const float*)d_in[3];
  const float* bh  = (const float*)d_in[4];
  const float* Why = (const float*)d_in[5];
  const float* by  = (const float*)d_in[6];
  float* out = (float*)d_out;

  char* ws = (char*)d_ws;
  size_t off = 0;
  float* EW0  = (float*)(ws + off); off += (size_t)V_ * H_ * 4;        // 256 KB
  u32* h0r    = (u32*)(ws + off);   off += (size_t)16 * PSLOT * 4;     // 4 MB
  u32* x1r    = (u32*)(ws + off);   off += (size_t)16 * PSLOT * 4;     // 4 MB
  u32* h1r    = (u32*)(ws + off);   off += (size_t)4 * PSLOT * 4;      // 1 MB
  u32* fa     = (u32*)(ws + off);   off += 4096;                       // progress arena
  u16* h1full = (u16*)(ws + off);   off += (size_t)B_ * S_ * H_ * 2;   // 67 MB

  // rings + progress must be zero each call: stale tags from a previous replay
  // are EXACTLY the values the next run polls for (tags are t+1 in [1,1024]).
  const size_t zlen = (size_t)(16 + 16 + 4) * PSLOT * 4 + 4096;
  hipMemsetAsync(h0r, 0, zlen, stream);

  k_embed<<<dim3(V_), dim3(256), 0, stream>>>(emb, Wxh, bh, EW0);

  k_pipe<<<dim3(48), dim3(512), 0, stream>>>(Whh, Wxh, ids, EW0, bh,
                                             h0r, x1r, h1r, h1full, fa);

  k_gemm_out<<<dim3((B_ * S_) / 64), dim3(256), 0, stream>>>(h1full, Why, by, out);
}